// Round 5
// baseline (123.117 us; speedup 1.0000x reference)
//
#include <hip/hip_runtime.h>

// LIF neuron forward scan, round 5: scalar + 1024-block + coherence barriers.
//
// x: (N=16, T=128, D=32768) fp32. Per (n,d): v = v*0.5 + x[t];
// spike = (v-1 >= 0); v -= spike (soft reset). Out: spikes, same shape.
//
// Round 4 (scalar, 8 waves/SIMD, prefetch8+NT) = 101.7 us = 5.3 TB/s = 84%
// of copy ceiling. Residual theory: per-wave 256 B-granular strided access
// (128 KB t-stride) degrades DRAM row locality as waves drift. This round:
//  - 1024-thread blocks: 4 KB contiguous per t-slab per block
//  - raw s_barrier per unroll group (NOT __syncthreads -- that would emit
//    s_waitcnt vmcnt(0) and drain the prefetch pipeline) to keep the
//    block's 16 waves phase-coherent -> 32 KB coherent bursts
//  - everything else identical (prefetch-8 pipeline, non-temporal, scalar)
// Occupancy unchanged: 512 blocks x 16 waves = 2 blocks/CU = 32 waves/CU.

constexpr int T_STEPS = 128;
constexpr int D_DIM   = 32768;
constexpr int LOG2_D  = 15;
constexpr int UNROLL  = 8;                 // t-steps per pipelined group
constexpr int NGROUPS = T_STEPS / UNROLL;  // 16

__device__ __forceinline__ float lif_step(float& v, float xin) {
    // v*0.5f is exact (exponent decrement): result matches numpy bit-for-bit
    // regardless of FMA contraction.
    v = v * 0.5f + xin;
    float u = v - 1.0f;                // reference: spike = 1[(v - V_TH) >= 0]
    bool s = (u >= 0.0f);
    v = s ? u : v;                     // soft reset == u exactly when spiking
    return s ? 1.0f : 0.0f;
}

__global__ __launch_bounds__(1024, 8) void lif_fwd(const float* __restrict__ x,
                                                   float* __restrict__ out,
                                                   int nd) {
    int idx = blockIdx.x * blockDim.x + threadIdx.x;
    if (idx >= nd) return;   // never taken for N*D = 512*1024 exactly

    int n = idx >> LOG2_D;
    int d = idx & (D_DIM - 1);
    size_t base = (size_t)n * T_STEPS * D_DIM + (size_t)d;

    const float* xp = x   + base;
    float*       op = out + base;

    float v = 0.0f;
    float cur[UNROLL], nxt[UNROLL];    // compile-time indices only

    // prologue: load group 0
#pragma unroll
    for (int i = 0; i < UNROLL; ++i)
        cur[i] = __builtin_nontemporal_load(&xp[(size_t)i * D_DIM]);

    for (int g = 1; g < NGROUPS; ++g) {
        const size_t gbase = (size_t)g * UNROLL * D_DIM;
        // issue next group's loads FIRST; they stay in flight while we
        // wait on / compute from the current group.
#pragma unroll
        for (int i = 0; i < UNROLL; ++i)
            nxt[i] = __builtin_nontemporal_load(&xp[gbase + (size_t)i * D_DIM]);

        // Raw barrier (no vmcnt drain): keep the block's 16 waves
        // phase-aligned at the load-issue point so the memory system sees
        // coherent 4 KB-per-t slabs. No inter-wave data exchange -> safe.
        __builtin_amdgcn_s_barrier();

        const size_t obase = (size_t)(g - 1) * UNROLL * D_DIM;
#pragma unroll
        for (int i = 0; i < UNROLL; ++i) {
            float s = lif_step(v, cur[i]);
            __builtin_nontemporal_store(s, &op[obase + (size_t)i * D_DIM]);
        }
#pragma unroll
        for (int i = 0; i < UNROLL; ++i)
            cur[i] = nxt[i];
    }

    // epilogue: last group
    const size_t obase = (size_t)(NGROUPS - 1) * UNROLL * D_DIM;
#pragma unroll
    for (int i = 0; i < UNROLL; ++i) {
        float s = lif_step(v, cur[i]);
        __builtin_nontemporal_store(s, &op[obase + (size_t)i * D_DIM]);
    }
}

extern "C" void kernel_launch(void* const* d_in, const int* in_sizes, int n_in,
                              void* d_out, int out_size, void* d_ws, size_t ws_size,
                              hipStream_t stream) {
    const float* x   = (const float*)d_in[0];
    float*       out = (float*)d_out;

    int nd = in_sizes[0] / T_STEPS;          // N*D = 524288 threads

    int block = 1024;
    int grid  = (nd + block - 1) / block;    // 512 blocks
    lif_fwd<<<grid, block, 0, stream>>>(x, out, nd);
}

// Round 6
// 86.661 us; speedup vs baseline: 1.4207x; 1.4207x over previous
//
#include <hip/hip_runtime.h>

// LIF neuron forward scan, round 6: round-4 structure, NT stores removed.
//
// x: (N=16, T=128, D=32768) fp32. Per (n,d): v = v*0.5 + x[t];
// spike = (v-1 >= 0); v -= spike (soft reset). Out: spikes, same shape.
//
// History: r1 f4-naive 129.7 | r3 f4+prefetch8+NT 117.3 | r4 scalar 8w/SIMD
// +prefetch8+NT 101.7 (5.3 TB/s, 84% of copy ceiling) | r5 1024-blk+barrier
// 123.1 REGRESS (reverted).
// This round, single-variable A/B vs r4: stores go back to NORMAL (L2
// write-allocate; the 6.9 TB/s harness memset uses normal stores -- NT
// no-allocate likely defeats L2 write buffering). Loads stay NT (zero
// reuse; keep read lines from evicting pending writes).

constexpr int T_STEPS = 128;
constexpr int D_DIM   = 32768;
constexpr int LOG2_D  = 15;
constexpr int UNROLL  = 8;                 // t-steps per pipelined group
constexpr int NGROUPS = T_STEPS / UNROLL;  // 16

__device__ __forceinline__ float lif_step(float& v, float xin) {
    // v*0.5f is exact (exponent decrement): result matches numpy bit-for-bit
    // regardless of FMA contraction.
    v = v * 0.5f + xin;
    float u = v - 1.0f;                // reference: spike = 1[(v - V_TH) >= 0]
    bool s = (u >= 0.0f);
    v = s ? u : v;                     // soft reset == u exactly when spiking
    return s ? 1.0f : 0.0f;
}

__global__ __launch_bounds__(256, 8) void lif_fwd(const float* __restrict__ x,
                                                  float* __restrict__ out,
                                                  int nd) {
    int idx = blockIdx.x * blockDim.x + threadIdx.x;
    if (idx >= nd) return;

    int n = idx >> LOG2_D;
    int d = idx & (D_DIM - 1);
    size_t base = (size_t)n * T_STEPS * D_DIM + (size_t)d;

    const float* xp = x   + base;
    float*       op = out + base;

    float v = 0.0f;
    float cur[UNROLL], nxt[UNROLL];    // compile-time indices only

    // prologue: load group 0
#pragma unroll
    for (int i = 0; i < UNROLL; ++i)
        cur[i] = __builtin_nontemporal_load(&xp[(size_t)i * D_DIM]);

    for (int g = 1; g < NGROUPS; ++g) {
        const size_t gbase = (size_t)g * UNROLL * D_DIM;
        // issue next group's loads FIRST; they stay in flight while we
        // wait on / compute from the current group.
#pragma unroll
        for (int i = 0; i < UNROLL; ++i)
            nxt[i] = __builtin_nontemporal_load(&xp[gbase + (size_t)i * D_DIM]);

        const size_t obase = (size_t)(g - 1) * UNROLL * D_DIM;
#pragma unroll
        for (int i = 0; i < UNROLL; ++i) {
            float s = lif_step(v, cur[i]);
            op[obase + (size_t)i * D_DIM] = s;   // NORMAL store (A/B vs r4)
        }
#pragma unroll
        for (int i = 0; i < UNROLL; ++i)
            cur[i] = nxt[i];
    }

    // epilogue: last group
    const size_t obase = (size_t)(NGROUPS - 1) * UNROLL * D_DIM;
#pragma unroll
    for (int i = 0; i < UNROLL; ++i) {
        float s = lif_step(v, cur[i]);
        op[obase + (size_t)i * D_DIM] = s;       // NORMAL store
    }
}

extern "C" void kernel_launch(void* const* d_in, const int* in_sizes, int n_in,
                              void* d_out, int out_size, void* d_ws, size_t ws_size,
                              hipStream_t stream) {
    const float* x   = (const float*)d_in[0];
    float*       out = (float*)d_out;

    int nd = in_sizes[0] / T_STEPS;          // N*D = 524288 threads

    int block = 256;
    int grid  = (nd + block - 1) / block;    // 2048 blocks
    lif_fwd<<<grid, block, 0, stream>>>(x, out, nd);
}